// Round 9
// baseline (648.691 us; speedup 1.0000x reference)
//
#include <hip/hip_runtime.h>

#define DD 8
#define HH 56
#define WW 56
#define HWW (HH*WW)
#define NTOK (DD*HH*WW)      // 25088
#define BB 4
#define CC 128
#define NH 8
#define HD 16
#define MTOT (BB*NTOK)       // 100352

typedef __attribute__((ext_vector_type(8))) short bf16x8;
typedef __attribute__((ext_vector_type(4))) float f32x4;

__device__ __forceinline__ unsigned short f2bf(float f){
    unsigned int u = __float_as_uint(f);
    u += 0x7FFFu + ((u>>16)&1u);
    return (unsigned short)(u>>16);
}
__device__ __forceinline__ float bf2f(unsigned short s){
    return __uint_as_float(((unsigned int)s)<<16);
}

// ---------- Pre-kernel: split weights into bf16 hi/lo pairs ----------
__global__ __launch_bounds__(256)
void wsplit_kernel(const float* __restrict__ qw, const float* __restrict__ kvw,
                   const float* __restrict__ pw,
                   unsigned short* __restrict__ whi, unsigned short* __restrict__ wlo,
                   unsigned short* __restrict__ pwhi, unsigned short* __restrict__ pwlo)
{
    int idx = blockIdx.x*256 + threadIdx.x;   // 0..65535
    if (idx < 49152){
        float s = (idx < 16384) ? qw[idx] : kvw[idx-16384];
        unsigned short h = f2bf(s);
        unsigned short l = f2bf(s - bf2f(h));
        whi[idx]=h; wlo[idx]=l;
    } else {
        int j = idx - 49152;                  // 0..16383
        float s = pw[j];
        unsigned short h = f2bf(s);
        unsigned short l = f2bf(s - bf2f(h));
        pwhi[j]=h; pwlo[j]=l;
    }
}

// ---------- Kernel A: QKV via 3-pass split-bf16 MFMA + q/k postprocess ----------
__global__ __launch_bounds__(256)
void qkv_kernel(const float* __restrict__ x,
                const float* __restrict__ qb, const float* __restrict__ kvb,
                const unsigned short* __restrict__ whi, const unsigned short* __restrict__ wlo,
                const float* __restrict__ temp, const float* __restrict__ qemb,
                float* __restrict__ qbuf, float* __restrict__ kbuf,
                unsigned short* __restrict__ vbuf)
{
    const int t  = threadIdx.x;
    const int wv = t>>6;
    const int l  = t&63;
    const int lr = l&15;     // A-row / B-col within tile; also C/D col
    const int lg = l>>4;     // k-group; C/D row-group
    const int m0 = blockIdx.x*64;

    f32x4 acc[4][6];
    #pragma unroll
    for (int j=0;j<6;++j){
        int col = (wv*6+j)*16 + lr;           // 0..383
        float b = (col<CC) ? qb[col] : kvb[col-CC];
        #pragma unroll
        for (int rt=0;rt<4;++rt) acc[rt][j] = (f32x4){b,b,b,b};
    }

    #pragma unroll
    for (int ks=0; ks<4; ++ks){
        bf16x8 ahi[4], alo[4];
        #pragma unroll
        for (int rt=0;rt<4;++rt){
            const float* xp = x + (size_t)(m0 + rt*16 + lr)*CC + ks*32 + lg*8;
            float4 xa = *reinterpret_cast<const float4*>(xp);
            float4 xb = *reinterpret_cast<const float4*>(xp+4);
            float xf[8] = {xa.x,xa.y,xa.z,xa.w, xb.x,xb.y,xb.z,xb.w};
            #pragma unroll
            for (int jj=0;jj<8;++jj){
                unsigned short h = f2bf(xf[jj]);
                unsigned short lo2 = f2bf(xf[jj] - bf2f(h));
                ahi[rt][jj] = (short)h;
                alo[rt][jj] = (short)lo2;
            }
        }
        #pragma unroll
        for (int j=0;j<6;++j){
            const int c = (wv*6+j)*16 + lr;   // weight row = output col
            const size_t off = (size_t)c*CC + ks*32 + lg*8;
            bf16x8 bhi = *reinterpret_cast<const bf16x8*>(whi + off);
            bf16x8 blo = *reinterpret_cast<const bf16x8*>(wlo + off);
            #pragma unroll
            for (int rt=0;rt<4;++rt){
                acc[rt][j] = __builtin_amdgcn_mfma_f32_16x16x32_bf16(ahi[rt], bhi, acc[rt][j], 0,0,0);
                acc[rt][j] = __builtin_amdgcn_mfma_f32_16x16x32_bf16(alo[rt], bhi, acc[rt][j], 0,0,0);
                acc[rt][j] = __builtin_amdgcn_mfma_f32_16x16x32_bf16(ahi[rt], blo, acc[rt][j], 0,0,0);
            }
        }
    }

    // ---- postprocess + store ----
    float slog[4][4];
    #pragma unroll
    for (int rt=0;rt<4;++rt){
        #pragma unroll
        for (int r=0;r<4;++r){
            int row = m0 + rt*16 + lg*4 + r;
            int n = row % NTOK;
            int z = n / HWW; int rem = n - z*HWW;
            int y = rem / WW; int xx = rem - y*WW;
            const float L2 = 0.69314718f, L3 = 1.09861229f;
            float sl = ((z==0||z==DD-1)?L2:L3) + ((y==0||y==HH-1)?L2:L3) + ((xx==0||xx==WW-1)?L2:L3);
            slog[rt][r] = sl;
        }
    }

    #pragma unroll
    for (int j=0;j<6;++j){
        const int ct  = wv*6+j;
        const int sel = ct>>3;                 // 0=q,1=k,2=v
        const int head = ct & 7;
        float vals[4][4];
        #pragma unroll
        for (int rt=0;rt<4;++rt){
            #pragma unroll
            for (int r=0;r<4;++r) vals[rt][r] = acc[rt][j][r];
        }
        if (sel < 2){
            // l2norm across the tile's 16 cols = across lanes sharing lg
            #pragma unroll
            for (int rt=0;rt<4;++rt){
                #pragma unroll
                for (int r=0;r<4;++r){
                    float s = vals[rt][r]*vals[rt][r];
                    s += __shfl_xor(s,1); s += __shfl_xor(s,2);
                    s += __shfl_xor(s,4); s += __shfl_xor(s,8);
                    float inv = 1.0f/fmaxf(sqrtf(s),1e-12f);
                    vals[rt][r] *= inv;
                }
            }
        }
        if (sel == 0){
            float tm = temp[head];
            float sps = (tm>15.f)?tm:log1pf(__expf(tm));
            float qe = qemb[head*HD + lr];
            #pragma unroll
            for (int rt=0;rt<4;++rt){
                #pragma unroll
                for (int r=0;r<4;++r)
                    vals[rt][r] = (vals[rt][r]+qe)*(slog[rt][r]*sps);
            }
        }
        #pragma unroll
        for (int rt=0;rt<4;++rt){
            #pragma unroll
            for (int r=0;r<4;++r){
                int row = m0 + rt*16 + lg*4 + r;
                if (sel==0){
                    qbuf[(size_t)row*CC + ct*16 + lr] = vals[rt][r];
                } else if (sel==1){
                    kbuf[(size_t)row*CC + (ct-8)*16 + lr] = vals[rt][r];
                } else {
                    vbuf[(size_t)row*CC + (ct-16)*16 + lr] = f2bf(vals[rt][r]);
                }
            }
        }
    }
}

// ---------- Kernel B: 27-neighbor attention (unchanged from baseline) ----------
__global__ __launch_bounds__(256)
void attn_kernel(float* __restrict__ qa,
                 const float* __restrict__ kbuf,
                 const unsigned short* __restrict__ vbuf,
                 const float* __restrict__ rpb)
{
    const int t = threadIdx.x;
    const int tok = blockIdx.x*32 + (t>>3);
    const int h = t&7;
    const int n = tok % NTOK;
    const int z = n / HWW; const int rem = n - z*HWW;
    const int y = rem / WW; const int xx = rem - y*WW;
    const int tokbase = tok - n;

    float qf[16];
    {
        const float4* qp = reinterpret_cast<const float4*>(qa + (size_t)tok*CC + h*HD);
        float4 a=qp[0],b=qp[1],c=qp[2],d=qp[3];
        qf[0]=a.x;qf[1]=a.y;qf[2]=a.z;qf[3]=a.w;
        qf[4]=b.x;qf[5]=b.y;qf[6]=b.z;qf[7]=b.w;
        qf[8]=c.x;qf[9]=c.y;qf[10]=c.z;qf[11]=c.w;
        qf[12]=d.x;qf[13]=d.y;qf[14]=d.z;qf[15]=d.w;
    }

    float l[27];
    #pragma unroll
    for (int j=0;j<27;++j){
        const int dz=j/9, dy=(j/3)%3, dx=j%3;
        int z2=z+dz-1, y2=y+dy-1, x2=xx+dx-1;
        bool valid = ((unsigned)z2<DD) && ((unsigned)y2<HH) && ((unsigned)x2<WW);
        int row2 = valid ? (tokbase + z2*HWW + y2*WW + x2) : tok;
        const float4* kp = reinterpret_cast<const float4*>(kbuf + (size_t)row2*CC + h*HD);
        float4 ka=kp[0],kb=kp[1],kc=kp[2],kd=kp[3];
        float kk[16]={ka.x,ka.y,ka.z,ka.w, kb.x,kb.y,kb.z,kb.w,
                      kc.x,kc.y,kc.z,kc.w, kd.x,kd.y,kd.z,kd.w};
        float s = 0.f;
        #pragma unroll
        for (int d=0;d<16;++d) s = fmaf(qf[d],kk[d],s);
        l[j] = valid ? (s + rpb[h*27+j]) : -1e30f;
    }

    float m = l[0];
    #pragma unroll
    for (int j=1;j<27;++j) m = fmaxf(m,l[j]);
    float sum=0.f;
    #pragma unroll
    for (int j=0;j<27;++j){ float e=__expf(l[j]-m); l[j]=e; sum+=e; }
    float rs = 1.0f/sum;

    float o[16];
    #pragma unroll
    for (int d=0;d<16;++d) o[d]=0.f;
    #pragma unroll
    for (int j=0;j<27;++j){
        const int dz=j/9, dy=(j/3)%3, dx=j%3;
        int z2=z+dz-1, y2=y+dy-1, x2=xx+dx-1;
        bool valid = ((unsigned)z2<DD) && ((unsigned)y2<HH) && ((unsigned)x2<WW);
        int row2 = valid ? (tokbase + z2*HWW + y2*WW + x2) : tok;
        const uint4* vp = reinterpret_cast<const uint4*>(vbuf + (size_t)row2*CC + h*HD);
        uint4 va=vp[0], vb=vp[1];
        unsigned int vw[8]={va.x,va.y,va.z,va.w,vb.x,vb.y,vb.z,vb.w};
        float w = l[j];
        #pragma unroll
        for (int q2=0;q2<8;++q2){
            o[2*q2]   = fmaf(w, bf2f((unsigned short)(vw[q2]&0xffffu)), o[2*q2]);
            o[2*q2+1] = fmaf(w, bf2f((unsigned short)(vw[q2]>>16)),     o[2*q2+1]);
        }
    }
    #pragma unroll
    for (int d=0;d<16;++d) o[d]*=rs;
    float4* op = reinterpret_cast<float4*>(qa + (size_t)tok*CC + h*HD);
    op[0]=make_float4(o[0],o[1],o[2],o[3]);
    op[1]=make_float4(o[4],o[5],o[6],o[7]);
    op[2]=make_float4(o[8],o[9],o[10],o[11]);
    op[3]=make_float4(o[12],o[13],o[14],o[15]);
}

// ---------- Kernel C: output projection via 3-pass split-bf16 MFMA ----------
__global__ __launch_bounds__(256)
void proj_kernel(const float* __restrict__ ao,
                 const unsigned short* __restrict__ pwhi, const unsigned short* __restrict__ pwlo,
                 const float* __restrict__ pb, float* __restrict__ out)
{
    const int t  = threadIdx.x;
    const int wv = t>>6;
    const int l  = t&63;
    const int lr = l&15;
    const int lg = l>>4;
    const int m0 = blockIdx.x*64;

    f32x4 acc[4][2];
    #pragma unroll
    for (int j=0;j<2;++j){
        float b = pb[(wv*2+j)*16 + lr];
        #pragma unroll
        for (int rt=0;rt<4;++rt) acc[rt][j] = (f32x4){b,b,b,b};
    }

    #pragma unroll
    for (int ks=0; ks<4; ++ks){
        bf16x8 ahi[4], alo[4];
        #pragma unroll
        for (int rt=0;rt<4;++rt){
            const float* xp = ao + (size_t)(m0 + rt*16 + lr)*CC + ks*32 + lg*8;
            float4 xa = *reinterpret_cast<const float4*>(xp);
            float4 xb = *reinterpret_cast<const float4*>(xp+4);
            float xf[8] = {xa.x,xa.y,xa.z,xa.w, xb.x,xb.y,xb.z,xb.w};
            #pragma unroll
            for (int jj=0;jj<8;++jj){
                unsigned short h = f2bf(xf[jj]);
                unsigned short lo2 = f2bf(xf[jj] - bf2f(h));
                ahi[rt][jj] = (short)h;
                alo[rt][jj] = (short)lo2;
            }
        }
        #pragma unroll
        for (int j=0;j<2;++j){
            const int c = (wv*2+j)*16 + lr;
            const size_t off = (size_t)c*CC + ks*32 + lg*8;
            bf16x8 bhi = *reinterpret_cast<const bf16x8*>(pwhi + off);
            bf16x8 blo = *reinterpret_cast<const bf16x8*>(pwlo + off);
            #pragma unroll
            for (int rt=0;rt<4;++rt){
                acc[rt][j] = __builtin_amdgcn_mfma_f32_16x16x32_bf16(ahi[rt], bhi, acc[rt][j], 0,0,0);
                acc[rt][j] = __builtin_amdgcn_mfma_f32_16x16x32_bf16(alo[rt], bhi, acc[rt][j], 0,0,0);
                acc[rt][j] = __builtin_amdgcn_mfma_f32_16x16x32_bf16(ahi[rt], blo, acc[rt][j], 0,0,0);
            }
        }
    }

    #pragma unroll
    for (int j=0;j<2;++j){
        const int col = (wv*2+j)*16 + lr;
        #pragma unroll
        for (int rt=0;rt<4;++rt){
            #pragma unroll
            for (int r=0;r<4;++r){
                int row = m0 + rt*16 + lg*4 + r;
                out[(size_t)row*CC + col] = acc[rt][j][r];
            }
        }
    }
}

extern "C" void kernel_launch(void* const* d_in, const int* in_sizes, int n_in,
                              void* d_out, int out_size, void* d_ws, size_t ws_size,
                              hipStream_t stream)
{
    const float* x    = (const float*)d_in[0];
    const float* qw   = (const float*)d_in[1];
    const float* qb   = (const float*)d_in[2];
    const float* kvw  = (const float*)d_in[3];
    const float* kvb  = (const float*)d_in[4];
    const float* pw   = (const float*)d_in[5];
    const float* pb   = (const float*)d_in[6];
    const float* temp = (const float*)d_in[7];
    const float* qemb = (const float*)d_in[8];
    const float* rpb  = (const float*)d_in[9];

    float* qbuf = (float*)d_ws;                                        // 51.4 MB
    float* kbuf = qbuf + (size_t)MTOT*CC;                              // 51.4 MB
    unsigned short* vbuf = (unsigned short*)(kbuf + (size_t)MTOT*CC);  // 25.7 MB
    unsigned short* whi  = vbuf + (size_t)MTOT*CC;                     // 96 KB
    unsigned short* wlo  = whi + 384*CC;
    unsigned short* pwhi = wlo + 384*CC;
    unsigned short* pwlo = pwhi + CC*CC;

    hipLaunchKernelGGL(wsplit_kernel, dim3(256), dim3(256), 0, stream,
                       qw,kvw,pw,whi,wlo,pwhi,pwlo);
    hipLaunchKernelGGL(qkv_kernel, dim3(MTOT/64), dim3(256), 0, stream,
                       x,qb,kvb,whi,wlo,temp,qemb,qbuf,kbuf,vbuf);
    hipLaunchKernelGGL(attn_kernel, dim3(MTOT/32), dim3(256), 0, stream,
                       qbuf,kbuf,vbuf,rpb);
    hipLaunchKernelGGL(proj_kernel, dim3(MTOT/64), dim3(256), 0, stream,
                       qbuf,pwhi,pwlo,pb,(float*)d_out);
}

// Round 11
// 456.424 us; speedup vs baseline: 1.4212x; 1.4212x over previous
//
#include <hip/hip_runtime.h>

#define DD 8
#define HH 56
#define WW 56
#define HWW (HH*WW)
#define NTOK (DD*HH*WW)      // 25088
#define BB 4
#define CC 128
#define NH 8
#define HD 16
#define MTOT (BB*NTOK)       // 100352

typedef __attribute__((ext_vector_type(8))) short bf16x8;
typedef __attribute__((ext_vector_type(4))) float f32x4;

__device__ __forceinline__ unsigned short f2bf(float f){
    unsigned int u = __float_as_uint(f);
    u += 0x7FFFu + ((u>>16)&1u);
    return (unsigned short)(u>>16);
}
__device__ __forceinline__ float bf2f(unsigned short s){
    return __uint_as_float(((unsigned int)s)<<16);
}

// ---------- Pre-kernel: weights -> FRAGMENT-ORDERED bf16 hi/lo ----------
// Fragment order: addr = ((ct*4+ks)*64 + lane)*8 + e, lane=lg*16+lr,
// holding w[col=ct*16+lr][k=ks*32+lg*8+e]. A wave's B-load is then 1KB contiguous.
__global__ __launch_bounds__(256)
void wsplit_kernel(const float* __restrict__ qw, const float* __restrict__ kvw,
                   const float* __restrict__ pw,
                   unsigned short* __restrict__ wfhi, unsigned short* __restrict__ wflo,
                   unsigned short* __restrict__ pwfhi, unsigned short* __restrict__ pwflo)
{
    int idx = blockIdx.x*256 + threadIdx.x;   // 0..65535
    int e  = idx&7;
    int l  = (idx>>3)&63;
    int ks = (idx>>9)&3;
    int ct = idx>>11;                         // 0..31
    int lr = l&15, lg = l>>4;
    int k  = ks*32 + lg*8 + e;
    if (ct < 24){                             // qkv weights: 384 cols
        int c = ct*16 + lr;
        float s = (c<CC) ? qw[c*CC+k] : kvw[(c-CC)*CC+k];
        unsigned short h = f2bf(s);
        unsigned short lo = f2bf(s - bf2f(h));
        wfhi[idx]=h; wflo[idx]=lo;            // idx == ((ct*4+ks)*64+l)*8+e
    } else {                                  // proj weights: 128 cols
        int c = (ct-24)*16 + lr;
        float s = pw[c*CC+k];
        unsigned short h = f2bf(s);
        unsigned short lo = f2bf(s - bf2f(h));
        int o = idx - 49152;
        pwfhi[o]=h; pwflo[o]=lo;
    }
}

// ---------- Kernel A: QKV, LDS-staged A + fragment-ordered B, 3-pass MFMA ----------
__global__ __launch_bounds__(256,3)
void qkv_kernel(const float* __restrict__ x,
                const float* __restrict__ qb, const float* __restrict__ kvb,
                const unsigned short* __restrict__ wfhi, const unsigned short* __restrict__ wflo,
                const float* __restrict__ temp, const float* __restrict__ qemb,
                float* __restrict__ qbuf, float* __restrict__ kbuf,
                unsigned short* __restrict__ vbuf)
{
    __shared__ float xs[64*128];              // 32KB, chunk-swizzled
    const int t  = threadIdx.x;
    const int wv = t>>6;
    const int l  = t&63;
    const int lr = l&15;
    const int lg = l>>4;
    const int m0 = blockIdx.x*64;

    // stage: coalesced global read, XOR-swizzled LDS write (chunk = 16B unit)
    #pragma unroll
    for (int i=0;i<8;++i){
        int p = i*256 + t;
        int row = p>>5, c = p&31;
        float4 v = *reinterpret_cast<const float4*>(x + (size_t)(m0+row)*CC + c*4);
        int ch = row*32 + (c ^ (row&7));
        *reinterpret_cast<float4*>(xs + ch*4) = v;
    }
    __syncthreads();

    f32x4 acc[4][6];
    #pragma unroll
    for (int j=0;j<6;++j){
        int col = (wv*6+j)*16 + lr;
        float b = (col<CC) ? qb[col] : kvb[col-CC];
        #pragma unroll
        for (int rt=0;rt<4;++rt) acc[rt][j] = (f32x4){b,b,b,b};
    }

    #pragma unroll
    for (int ks=0; ks<4; ++ks){
        bf16x8 ahi[4], alo[4];
        #pragma unroll
        for (int rt=0;rt<4;++rt){
            int row = rt*16 + lr;
            int c0  = ks*8 + lg*2;
            float4 a0 = *reinterpret_cast<const float4*>(xs + (row*32 + ( c0   ^(row&7)))*4);
            float4 a1 = *reinterpret_cast<const float4*>(xs + (row*32 + ((c0+1)^(row&7)))*4);
            float xf[8] = {a0.x,a0.y,a0.z,a0.w, a1.x,a1.y,a1.z,a1.w};
            #pragma unroll
            for (int jj=0;jj<8;++jj){
                unsigned short h = f2bf(xf[jj]);
                unsigned short lo2 = f2bf(xf[jj] - bf2f(h));
                ahi[rt][jj] = (short)h;
                alo[rt][jj] = (short)lo2;
            }
        }
        #pragma unroll
        for (int j=0;j<6;++j){
            const int ct = wv*6+j;
            const size_t off = (size_t)(((ct*4+ks)*64 + l))*8;
            bf16x8 bhi = *reinterpret_cast<const bf16x8*>(wfhi + off);
            bf16x8 blo = *reinterpret_cast<const bf16x8*>(wflo + off);
            #pragma unroll
            for (int rt=0;rt<4;++rt){
                acc[rt][j] = __builtin_amdgcn_mfma_f32_16x16x32_bf16(ahi[rt], bhi, acc[rt][j], 0,0,0);
                acc[rt][j] = __builtin_amdgcn_mfma_f32_16x16x32_bf16(alo[rt], bhi, acc[rt][j], 0,0,0);
                acc[rt][j] = __builtin_amdgcn_mfma_f32_16x16x32_bf16(ahi[rt], blo, acc[rt][j], 0,0,0);
            }
        }
    }

    // ---- postprocess + store (verified in round 9) ----
    float slog[4][4];
    #pragma unroll
    for (int rt=0;rt<4;++rt){
        #pragma unroll
        for (int r=0;r<4;++r){
            int row = m0 + rt*16 + lg*4 + r;
            int n = row % NTOK;
            int z = n / HWW; int rem = n - z*HWW;
            int y = rem / WW; int xx = rem - y*WW;
            const float L2c = 0.69314718f, L3c = 1.09861229f;
            float sl = ((z==0||z==DD-1)?L2c:L3c) + ((y==0||y==HH-1)?L2c:L3c) + ((xx==0||xx==WW-1)?L2c:L3c);
            slog[rt][r] = sl;
        }
    }

    #pragma unroll
    for (int j=0;j<6;++j){
        const int ct  = wv*6+j;
        const int sel = ct>>3;                 // 0=q,1=k,2=v
        const int head = ct & 7;
        float vals[4][4];
        #pragma unroll
        for (int rt=0;rt<4;++rt){
            #pragma unroll
            for (int r=0;r<4;++r) vals[rt][r] = acc[rt][j][r];
        }
        if (sel < 2){
            #pragma unroll
            for (int rt=0;rt<4;++rt){
                #pragma unroll
                for (int r=0;r<4;++r){
                    float s = vals[rt][r]*vals[rt][r];
                    s += __shfl_xor(s,1); s += __shfl_xor(s,2);
                    s += __shfl_xor(s,4); s += __shfl_xor(s,8);
                    float inv = 1.0f/fmaxf(sqrtf(s),1e-12f);
                    vals[rt][r] *= inv;
                }
            }
        }
        if (sel == 0){
            float tm = temp[head];
            float sps = (tm>15.f)?tm:log1pf(__expf(tm));
            float qe = qemb[head*HD + lr];
            #pragma unroll
            for (int rt=0;rt<4;++rt){
                #pragma unroll
                for (int r=0;r<4;++r)
                    vals[rt][r] = (vals[rt][r]+qe)*(slog[rt][r]*sps);
            }
        }
        #pragma unroll
        for (int rt=0;rt<4;++rt){
            #pragma unroll
            for (int r=0;r<4;++r){
                int row = m0 + rt*16 + lg*4 + r;
                if (sel==0){
                    qbuf[(size_t)row*CC + ct*16 + lr] = vals[rt][r];
                } else if (sel==1){
                    kbuf[(size_t)row*CC + (ct-8)*16 + lr] = vals[rt][r];
                } else {
                    vbuf[(size_t)row*CC + (ct-16)*16 + lr] = f2bf(vals[rt][r]);
                }
            }
        }
    }
}

// ---------- Kernel B: 27-neighbor attention (byte-identical, measured-working) ----------
__global__ __launch_bounds__(256)
void attn_kernel(float* __restrict__ qa,
                 const float* __restrict__ kbuf,
                 const unsigned short* __restrict__ vbuf,
                 const float* __restrict__ rpb)
{
    const int t = threadIdx.x;
    const int tok = blockIdx.x*32 + (t>>3);
    const int h = t&7;
    const int n = tok % NTOK;
    const int z = n / HWW; const int rem = n - z*HWW;
    const int y = rem / WW; const int xx = rem - y*WW;
    const int tokbase = tok - n;

    float qf[16];
    {
        const float4* qp = reinterpret_cast<const float4*>(qa + (size_t)tok*CC + h*HD);
        float4 a=qp[0],b=qp[1],c=qp[2],d=qp[3];
        qf[0]=a.x;qf[1]=a.y;qf[2]=a.z;qf[3]=a.w;
        qf[4]=b.x;qf[5]=b.y;qf[6]=b.z;qf[7]=b.w;
        qf[8]=c.x;qf[9]=c.y;qf[10]=c.z;qf[11]=c.w;
        qf[12]=d.x;qf[13]=d.y;qf[14]=d.z;qf[15]=d.w;
    }

    float l[27];
    #pragma unroll
    for (int j=0;j<27;++j){
        const int dz=j/9, dy=(j/3)%3, dx=j%3;
        int z2=z+dz-1, y2=y+dy-1, x2=xx+dx-1;
        bool valid = ((unsigned)z2<DD) && ((unsigned)y2<HH) && ((unsigned)x2<WW);
        int row2 = valid ? (tokbase + z2*HWW + y2*WW + x2) : tok;
        const float4* kp = reinterpret_cast<const float4*>(kbuf + (size_t)row2*CC + h*HD);
        float4 ka=kp[0],kb=kp[1],kc=kp[2],kd=kp[3];
        float kk[16]={ka.x,ka.y,ka.z,ka.w, kb.x,kb.y,kb.z,kb.w,
                      kc.x,kc.y,kc.z,kc.w, kd.x,kd.y,kd.z,kd.w};
        float s = 0.f;
        #pragma unroll
        for (int d=0;d<16;++d) s = fmaf(qf[d],kk[d],s);
        l[j] = valid ? (s + rpb[h*27+j]) : -1e30f;
    }

    float m = l[0];
    #pragma unroll
    for (int j=1;j<27;++j) m = fmaxf(m,l[j]);
    float sum=0.f;
    #pragma unroll
    for (int j=0;j<27;++j){ float e=__expf(l[j]-m); l[j]=e; sum+=e; }
    float rs = 1.0f/sum;

    float o[16];
    #pragma unroll
    for (int d=0;d<16;++d) o[d]=0.f;
    #pragma unroll
    for (int j=0;j<27;++j){
        const int dz=j/9, dy=(j/3)%3, dx=j%3;
        int z2=z+dz-1, y2=y+dy-1, x2=xx+dx-1;
        bool valid = ((unsigned)z2<DD) && ((unsigned)y2<HH) && ((unsigned)x2<WW);
        int row2 = valid ? (tokbase + z2*HWW + y2*WW + x2) : tok;
        const uint4* vp = reinterpret_cast<const uint4*>(vbuf + (size_t)row2*CC + h*HD);
        uint4 va=vp[0], vb=vp[1];
        unsigned int vw[8]={va.x,va.y,va.z,va.w,vb.x,vb.y,vb.z,vb.w};
        float w = l[j];
        #pragma unroll
        for (int q2=0;q2<8;++q2){
            o[2*q2]   = fmaf(w, bf2f((unsigned short)(vw[q2]&0xffffu)), o[2*q2]);
            o[2*q2+1] = fmaf(w, bf2f((unsigned short)(vw[q2]>>16)),     o[2*q2+1]);
        }
    }
    #pragma unroll
    for (int d=0;d<16;++d) o[d]*=rs;
    float4* op = reinterpret_cast<float4*>(qa + (size_t)tok*CC + h*HD);
    op[0]=make_float4(o[0],o[1],o[2],o[3]);
    op[1]=make_float4(o[4],o[5],o[6],o[7]);
    op[2]=make_float4(o[8],o[9],o[10],o[11]);
    op[3]=make_float4(o[12],o[13],o[14],o[15]);
}

// ---------- Kernel C: proj, LDS-staged plain-bf16 A + split-B (2-pass MFMA) ----------
__global__ __launch_bounds__(256,4)
void proj_kernel(const float* __restrict__ ao,
                 const unsigned short* __restrict__ pwfhi, const unsigned short* __restrict__ pwflo,
                 const float* __restrict__ pb, float* __restrict__ out)
{
    __shared__ float xs[64*128];
    const int t  = threadIdx.x;
    const int wv = t>>6;
    const int l  = t&63;
    const int lr = l&15;
    const int lg = l>>4;
    const int m0 = blockIdx.x*64;

    #pragma unroll
    for (int i=0;i<8;++i){
        int p = i*256 + t;
        int row = p>>5, c = p&31;
        float4 v = *reinterpret_cast<const float4*>(ao + (size_t)(m0+row)*CC + c*4);
        int ch = row*32 + (c ^ (row&7));
        *reinterpret_cast<float4*>(xs + ch*4) = v;
    }
    __syncthreads();

    f32x4 acc[4][2];
    #pragma unroll
    for (int j=0;j<2;++j){
        float b = pb[(wv*2+j)*16 + lr];
        #pragma unroll
        for (int rt=0;rt<4;++rt) acc[rt][j] = (f32x4){b,b,b,b};
    }

    #pragma unroll
    for (int ks=0; ks<4; ++ks){
        bf16x8 ahi[4];
        #pragma unroll
        for (int rt=0;rt<4;++rt){
            int row = rt*16 + lr;
            int c0  = ks*8 + lg*2;
            float4 a0 = *reinterpret_cast<const float4*>(xs + (row*32 + ( c0   ^(row&7)))*4);
            float4 a1 = *reinterpret_cast<const float4*>(xs + (row*32 + ((c0+1)^(row&7)))*4);
            float xf[8] = {a0.x,a0.y,a0.z,a0.w, a1.x,a1.y,a1.z,a1.w};
            #pragma unroll
            for (int jj=0;jj<8;++jj) ahi[rt][jj] = (short)f2bf(xf[jj]);
        }
        #pragma unroll
        for (int j=0;j<2;++j){
            const int ct = wv*2+j;
            const size_t off = (size_t)(((ct*4+ks)*64 + l))*8;
            bf16x8 bhi = *reinterpret_cast<const bf16x8*>(pwfhi + off);
            bf16x8 blo = *reinterpret_cast<const bf16x8*>(pwflo + off);
            #pragma unroll
            for (int rt=0;rt<4;++rt){
                acc[rt][j] = __builtin_amdgcn_mfma_f32_16x16x32_bf16(ahi[rt], bhi, acc[rt][j], 0,0,0);
                acc[rt][j] = __builtin_amdgcn_mfma_f32_16x16x32_bf16(ahi[rt], blo, acc[rt][j], 0,0,0);
            }
        }
    }

    #pragma unroll
    for (int j=0;j<2;++j){
        const int col = (wv*2+j)*16 + lr;
        #pragma unroll
        for (int rt=0;rt<4;++rt){
            #pragma unroll
            for (int r=0;r<4;++r){
                int row = m0 + rt*16 + lg*4 + r;
                out[(size_t)row*CC + col] = acc[rt][j][r];
            }
        }
    }
}

extern "C" void kernel_launch(void* const* d_in, const int* in_sizes, int n_in,
                              void* d_out, int out_size, void* d_ws, size_t ws_size,
                              hipStream_t stream)
{
    const float* x    = (const float*)d_in[0];
    const float* qw   = (const float*)d_in[1];
    const float* qb   = (const float*)d_in[2];
    const float* kvw  = (const float*)d_in[3];
    const float* kvb  = (const float*)d_in[4];
    const float* pw   = (const float*)d_in[5];
    const float* pb   = (const float*)d_in[6];
    const float* temp = (const float*)d_in[7];
    const float* qemb = (const float*)d_in[8];
    const float* rpb  = (const float*)d_in[9];

    float* qbuf = (float*)d_ws;                                        // 51.4 MB
    float* kbuf = qbuf + (size_t)MTOT*CC;                              // 51.4 MB
    unsigned short* vbuf = (unsigned short*)(kbuf + (size_t)MTOT*CC);  // 25.7 MB
    unsigned short* wfhi  = vbuf + (size_t)MTOT*CC;                    // 96 KB
    unsigned short* wflo  = wfhi + 384*CC;
    unsigned short* pwfhi = wflo + 384*CC;
    unsigned short* pwflo = pwfhi + CC*CC;

    hipLaunchKernelGGL(wsplit_kernel, dim3(256), dim3(256), 0, stream,
                       qw,kvw,pw,wfhi,wflo,pwfhi,pwflo);
    hipLaunchKernelGGL(qkv_kernel, dim3(MTOT/64), dim3(256), 0, stream,
                       x,qb,kvb,wfhi,wflo,temp,qemb,qbuf,kbuf,vbuf);
    hipLaunchKernelGGL(attn_kernel, dim3(MTOT/32), dim3(256), 0, stream,
                       qbuf,kbuf,vbuf,rpb);
    hipLaunchKernelGGL(proj_kernel, dim3(MTOT/64), dim3(256), 0, stream,
                       qbuf,pwfhi,pwflo,pb,(float*)d_out);
}